// Round 15
// baseline (116.902 us; speedup 1.0000x reference)
//
#include <hip/hip_runtime.h>
#include <hip/hip_bf16.h>
#include <math.h>

#define FEAT 384
#define FFN  768
#define ZDIM 384
#define HID  192
#define BB   4
#define NN   128
#define BN   (BB*NN)   // 512 rows

__device__ __forceinline__ float gelu_exact(float x) {
    return 0.5f * x * (1.0f + erff(x * 0.70710678118654752440f));
}

__device__ __forceinline__ float bflo(unsigned u) { return __uint_as_float(u << 16); }
__device__ __forceinline__ float bfhi(unsigned u) { return __uint_as_float(u & 0xFFFF0000u); }

template<bool F32>
__device__ __forceinline__ float ldg(const void* p, int i) {
    if constexpr (F32) return ((const float*)p)[i];
    return __uint_as_float(((unsigned)((const unsigned short*)p)[i]) << 16);
}
template<bool F32>
__device__ __forceinline__ void stg(void* p, size_t i, float v) {
    if constexpr (F32) ((float*)p)[i] = v;
    else ((__hip_bfloat16*)p)[i] = __float2bfloat16(v);
}

// weight-vector loaders
template<bool F32> struct V4;
template<> struct V4<true> {
    float4 a;
    __device__ __forceinline__ void load(const void* p, size_t off) {
        a = *(const float4*)((const float*)p + off);
    }
    __device__ __forceinline__ float g(int i) const { return (&a.x)[i]; }
};
template<> struct V4<false> {
    uint2 u;
    __device__ __forceinline__ void load(const void* p, size_t off) {
        u = *(const uint2*)((const unsigned short*)p + off);
    }
    __device__ __forceinline__ float g(int i) const {
        const unsigned w = (&u.x)[i >> 1];
        return (i & 1) ? bfhi(w) : bflo(w);
    }
};
template<bool F32> struct V2;
template<> struct V2<true> {
    float2 a;
    __device__ __forceinline__ void load(const void* p, size_t off) {
        a = *(const float2*)((const float*)p + off);
    }
    __device__ __forceinline__ float g(int i) const { return (&a.x)[i]; }
};
template<> struct V2<false> {
    unsigned u;
    __device__ __forceinline__ void load(const void* p, size_t off) {
        u = *(const unsigned*)((const unsigned short*)p + off);
    }
    __device__ __forceinline__ float g(int i) const {
        return i ? bfhi(u) : bflo(u);
    }
};

__device__ __forceinline__ bool is_f32(const void* ln_w) {
    return ((const unsigned short*)ln_w)[0] == 0;
}

// ---- block reductions over 384 threads (6 wave64) ----
__device__ __forceinline__ float block_sum(float v, float* sm) {
    for (int o = 32; o > 0; o >>= 1) v += __shfl_down(v, o, 64);
    const int lane = threadIdx.x & 63, w = threadIdx.x >> 6;
    __syncthreads();
    if (lane == 0) sm[w] = v;
    __syncthreads();
    return sm[0] + sm[1] + sm[2] + sm[3] + sm[4] + sm[5];
}
__device__ __forceinline__ float block_max(float v, float* sm) {
    for (int o = 32; o > 0; o >>= 1) v = fmaxf(v, __shfl_down(v, o, 64));
    const int lane = threadIdx.x & 63, w = threadIdx.x >> 6;
    __syncthreads();
    if (lane == 0) sm[w] = v;
    __syncthreads();
    return fmaxf(fmaxf(fmaxf(sm[0], sm[1]), fmaxf(sm[2], sm[3])), fmaxf(sm[4], sm[5]));
}
// N-wide block sum; sm must hold 6*N floats
template<int N>
__device__ __forceinline__ void block_sumN(const float v[N], float* sm, float out[N]) {
    float tv[N];
    #pragma unroll
    for (int n = 0; n < N; n++) tv[n] = v[n];
    for (int o = 32; o > 0; o >>= 1) {
        #pragma unroll
        for (int n = 0; n < N; n++) tv[n] += __shfl_down(tv[n], o, 64);
    }
    const int lane = threadIdx.x & 63, w = threadIdx.x >> 6;
    __syncthreads();
    if (lane == 0) {
        #pragma unroll
        for (int n = 0; n < N; n++) sm[n * 6 + w] = tv[n];
    }
    __syncthreads();
    #pragma unroll
    for (int n = 0; n < N; n++)
        out[n] = sm[n*6] + sm[n*6+1] + sm[n*6+2] + sm[n*6+3] + sm[n*6+4] + sm[n*6+5];
}

// Shared pool (floats): xs 0 (3072), zs 3072 (3072), hid 6144 (1536),
// gh 7680 (192) [contiguous after hid => row 8 of decoder input],
// part 7872 (9216), sm 17088 (48). Total 17136 = 68.5 KB.
#define SM_TOTAL 17136

// Generic GEMM, 3-deep rotating weight staging:
// M rows from LDS (in[m*ldin+k]), C cols/thread via loader VL, K-chunk KCH.
template<bool F32, int KCH, int M, int C, template<bool> class VL>
__device__ __forceinline__ void gemmG(
    const void* __restrict__ W, int ldw, int c0, int kb,
    const float* __restrict__ in, int ldin, float acc[M][C])
{
    constexpr int NB = KCH / 8;
    VL<F32> buf[3][8];
    #pragma unroll
    for (int j = 0; j < 8; j++) buf[0][j].load(W, (size_t)(kb + j) * ldw + c0);
    if (NB > 1) {
        #pragma unroll
        for (int j = 0; j < 8; j++) buf[1][j].load(W, (size_t)(kb + 8 + j) * ldw + c0);
    }
    #pragma unroll
    for (int b = 0; b < NB; b++) {
        const int cur = b % 3;
        if (b + 2 < NB) {
            const int nxt = (b + 2) % 3;
            #pragma unroll
            for (int j = 0; j < 8; j++)
                buf[nxt][j].load(W, (size_t)(kb + (b + 2) * 8 + j) * ldw + c0);
        }
        #pragma unroll
        for (int j = 0; j < 8; j++) {
            #pragma unroll
            for (int m = 0; m < M; m++) {
                const float xv = in[m * ldin + kb + b * 8 + j];
                #pragma unroll
                for (int i = 0; i < C; i++)
                    acc[m][i] = fmaf(xv, buf[cur][j].g(i), acc[m][i]);
            }
        }
    }
}

// ============ Type A: octet q — U z-half -> LN -> enc -> dec -> dots ============
template<bool F32>
__device__ void bodyA(float* S, int q,
    const void* __restrict__ x, const void* __restrict__ U_w,
    const void* __restrict__ U_b, const void* __restrict__ ln_w,
    const void* __restrict__ ln_b, const void* __restrict__ enc_w,
    const void* __restrict__ enc_b, const void* __restrict__ dec_w,
    const void* __restrict__ dec_b,
    float* __restrict__ d0, float* __restrict__ diag)
{
    const int rb = 8 * q;
    const int t = threadIdx.x;
    float* xs = S;           // 8 x 384
    float* zs = S + 3072;    // 8 x 384
    float* hid = S + 6144;   // 8 x 192 (+ gh after = row 8)
    float* gh = S + 7680;    // 192
    float* part = S + 7872;  // 9216
    float* sm = S + 17088;   // 48

    #pragma unroll
    for (int m = 0; m < 8; m++) xs[m * 384 + t] = ldg<F32>(x, (rb + m) * FEAT + t);
    if (t < HID) gh[t] = gelu_exact(ldg<F32>(enc_b, t));
    __syncthreads();

    // ---- U z-half: cg=t%96 -> 4 cols (global 384+4cg); kh=t/96 -> K 96kh..+96 ----
    const int cg = t % 96, kh = t / 96;
    const int cL = 4 * cg, cG = ZDIM + cL, kb = 96 * kh;
    float acc[8][4] = {};
    gemmG<F32, 96, 8, 4, V4>(U_w, FFN, cG, kb, xs, 384, acc);
    if (kh > 0) {
        float* p = &part[(kh - 1) * 3072 + cg];
        #pragma unroll
        for (int m = 0; m < 8; m++)
            #pragma unroll
            for (int i = 0; i < 4; i++) p[(m * 4 + i) * 96] = acc[m][i];
    }
    __syncthreads();

    float hv[8][4];
    float s1[8] = {}, s2[8] = {};
    if (kh == 0) {
        #pragma unroll
        for (int i = 0; i < 4; i++) {
            const float ub = ldg<F32>(U_b, cG + i);
            #pragma unroll
            for (int m = 0; m < 8; m++) {
                float v = acc[m][i] + ub
                        + part[(m * 4 + i) * 96 + cg]
                        + part[3072 + (m * 4 + i) * 96 + cg]
                        + part[6144 + (m * 4 + i) * 96 + cg];
                v = gelu_exact(v);
                hv[m][i] = v;
                s1[m] += v; s2[m] += v * v;
            }
        }
    }
    float S1[8], S2[8];
    block_sumN<8>(s1, sm, S1);
    block_sumN<8>(s2, sm, S2);
    if (kh == 0) {
        #pragma unroll
        for (int m = 0; m < 8; m++) {
            const float mu = S1[m] * (1.0f / ZDIM);
            const float rs = rsqrtf(S2[m] * (1.0f / ZDIM) - mu * mu + 1e-5f);
            #pragma unroll
            for (int i = 0; i < 4; i++) {
                const int zc = cL + i;
                zs[m * 384 + zc] = (hv[m][i] - mu) * rs * ldg<F32>(ln_w, zc) + ldg<F32>(ln_b, zc);
            }
        }
    }
    __syncthreads();

    // ---- encoder: cgE=t%96 -> 2 cols of 192; khE=t/96 -> K 96khE..+96 ----
    {
        const int cgE = t % 96, khE = t / 96;
        const int cE = 2 * cgE, kbE = 96 * khE;
        float ea[8][2] = {};
        gemmG<F32, 96, 8, 2, V2>(enc_w, HID, cE, kbE, zs, 384, ea);
        if (khE > 0) {
            float* p = &part[(khE - 1) * 1536 + cgE];
            #pragma unroll
            for (int m = 0; m < 8; m++)
                #pragma unroll
                for (int i = 0; i < 2; i++) p[(m * 2 + i) * 96] = ea[m][i];
        }
        __syncthreads();
        if (khE == 0) {
            #pragma unroll
            for (int i = 0; i < 2; i++) {
                const float ebv = ldg<F32>(enc_b, cE + i);
                #pragma unroll
                for (int m = 0; m < 8; m++) {
                    float v = ea[m][i] + ebv;
                    #pragma unroll
                    for (int kk = 0; kk < 3; kk++)
                        v += part[kk * 1536 + (m * 2 + i) * 96 + cgE];
                    hid[m * 192 + cE + i] = gelu_exact(v);
                }
            }
        }
        __syncthreads();
    }

    // ---- decoder: 9-row GEMM (8 hid rows + gh row); cgD=t%192 -> 2 cols of 384;
    //      khD=t/192 -> K 96khD..+96 (K total 192) ----
    {
        const int cgD = t % 192, khD = t / 192;
        const int cD = 2 * cgD, kbD = 96 * khD;
        float da[9][2] = {};
        gemmG<F32, 96, 9, 2, V2>(dec_w, ZDIM, cD, kbD, hid, 192, da);
        if (khD > 0) {
            float* p = &part[cgD];
            #pragma unroll
            for (int m = 0; m < 9; m++)
                #pragma unroll
                for (int i = 0; i < 2; i++) p[(m * 2 + i) * 192] = da[m][i];
        }
        __syncthreads();
        float pd[8] = {}, pe[8] = {};
        if (khD == 0) {
            #pragma unroll
            for (int i = 0; i < 2; i++) {
                const int c = cD + i;
                const float dbv = ldg<F32>(dec_b, c);
                float vc = da[8][i] + dbv + part[(16 + i) * 192 + cgD];
                #pragma unroll
                for (int m = 0; m < 8; m++) {
                    const float v = da[m][i] + dbv + part[(m * 2 + i) * 192 + cgD];
                    const float zv = zs[m * 384 + c];
                    pd[m] = fmaf(v, zv, pd[m]);
                    pe[m] = fmaf(vc, zv, pe[m]);
                }
            }
        }
        float DG[8], DD[8];
        block_sumN<8>(pd, sm, DG);
        block_sumN<8>(pe, sm, DD);
        if (t == 0) {
            #pragma unroll
            for (int m = 0; m < 8; m++) { diag[rb + m] = DG[m]; d0[rb + m] = DD[m]; }
        }
    }
}

// ============ Type B: octet q — U xh-half -> Y = xh @ V_w ============
template<bool F32>
__device__ void bodyB(float* S, int q,
    const void* __restrict__ x, const void* __restrict__ U_w,
    const void* __restrict__ U_b, const void* __restrict__ V_w,
    float* __restrict__ Y)
{
    const int rb = 8 * q;
    const int t = threadIdx.x;
    float* xs = S;           // 8 x 384
    float* zs = S + 3072;    // 8 x 384 (xh)
    float* part = S + 7872;  // 9216

    #pragma unroll
    for (int m = 0; m < 8; m++) xs[m * 384 + t] = ldg<F32>(x, (rb + m) * FEAT + t);
    __syncthreads();

    const int cg = t % 96, kh = t / 96;
    const int cL = 4 * cg, kb = 96 * kh;
    float acc[8][4] = {};
    gemmG<F32, 96, 8, 4, V4>(U_w, FFN, cL, kb, xs, 384, acc);
    if (kh > 0) {
        float* p = &part[(kh - 1) * 3072 + cg];
        #pragma unroll
        for (int m = 0; m < 8; m++)
            #pragma unroll
            for (int i = 0; i < 4; i++) p[(m * 4 + i) * 96] = acc[m][i];
    }
    __syncthreads();
    if (kh == 0) {
        #pragma unroll
        for (int i = 0; i < 4; i++) {
            const float ub = ldg<F32>(U_b, cL + i);
            #pragma unroll
            for (int m = 0; m < 8; m++) {
                float v = acc[m][i] + ub
                        + part[(m * 4 + i) * 96 + cg]
                        + part[3072 + (m * 4 + i) * 96 + cg]
                        + part[6144 + (m * 4 + i) * 96 + cg];
                zs[m * 384 + cL + i] = gelu_exact(v);
            }
        }
    }
    __syncthreads();

    // V: K = 384 full; same mapping
    float ya[8][4] = {};
    gemmG<F32, 96, 8, 4, V4>(V_w, FEAT, cL, kb, zs, 384, ya);
    if (kh > 0) {
        float* p = &part[(kh - 1) * 3072 + cg];
        #pragma unroll
        for (int m = 0; m < 8; m++)
            #pragma unroll
            for (int i = 0; i < 4; i++) p[(m * 4 + i) * 96] = ya[m][i];
    }
    __syncthreads();
    if (kh == 0) {
        #pragma unroll
        for (int m = 0; m < 8; m++) {
            float o[4];
            #pragma unroll
            for (int i = 0; i < 4; i++) {
                o[i] = ya[m][i]
                     + part[(m * 4 + i) * 96 + cg]
                     + part[3072 + (m * 4 + i) * 96 + cg]
                     + part[6144 + (m * 4 + i) * 96 + cg];
            }
            *(float4*)(Y + (size_t)(rb + m) * FEAT + cL) = make_float4(o[0], o[1], o[2], o[3]);
        }
    }
}

__global__ __launch_bounds__(384) void k_main(
    const void* x, const void* U_w, const void* U_b,
    const void* ln_w, const void* ln_b,
    const void* enc_w, const void* enc_b,
    const void* dec_w, const void* dec_b, const void* V_w,
    float* Y, float* d0, float* diag)
{
    __shared__ float S[SM_TOTAL];   // single pool for all template paths
    const int type = blockIdx.x & 1;
    const int q = blockIdx.x >> 1;   // octet 0..63
    if (is_f32(ln_w)) {
        if (type == 0) bodyA<true >(S, q, x, U_w, U_b, ln_w, ln_b, enc_w, enc_b, dec_w, dec_b, d0, diag);
        else           bodyB<true >(S, q, x, U_w, U_b, V_w, Y);
    } else {
        if (type == 0) bodyA<false>(S, q, x, U_w, U_b, ln_w, ln_b, enc_w, enc_b, dec_w, dec_b, d0, diag);
        else           bodyB<false>(S, q, x, U_w, U_b, V_w, Y);
    }
}

// ============ K2: 16 blocks = 4 batches x 4 col-chunks of 96 ============
// out_i = (baseY + (ed_i - e0_i) * Y_i) / (S - e0_i + ed_i) + V_b
template<bool F32>
__device__ void combine_body(
    const float* __restrict__ d0, const float* __restrict__ diag,
    const float* __restrict__ Y,
    const void* __restrict__ V_b, void* __restrict__ out)
{
    const int b  = blockIdx.x >> 2;
    const int cc = (blockIdx.x & 3) * 96;
    const int t = threadIdx.x;
    const int c = t % 96, qq = t / 96;
    __shared__ float e0s[NN], eds[NN];
    __shared__ float bp[4 * 96];
    __shared__ float baseY[96];
    __shared__ float sm[12];

    float d0v = -INFINITY, dgv = -INFINITY;
    if (t < NN) { d0v = d0[b * NN + t]; dgv = diag[b * NN + t]; }
    const float m = block_max(fmaxf(d0v, dgv), sm);
    float e0v = 0.f;
    if (t < NN) {
        e0v = expf(d0v - m);
        e0s[t] = e0v;
        eds[t] = expf(dgv - m);
    }
    const float S = block_sum(e0v, sm);

    const float* Yb = Y + (size_t)b * NN * FEAT + cc + c;
    const int j0 = 32 * qq;
    float p = 0.f;
    for (int jj = 0; jj < 32; jj += 8) {
        float w[8];
        #pragma unroll
        for (int j = 0; j < 8; j++) w[j] = Yb[(size_t)(j0 + jj + j) * FEAT];
        #pragma unroll
        for (int j = 0; j < 8; j++) p = fmaf(e0s[j0 + jj + j], w[j], p);
    }
    bp[qq * 96 + c] = p;
    __syncthreads();
    if (qq == 0) baseY[c] = bp[c] + bp[96 + c] + bp[192 + c] + bp[288 + c];
    __syncthreads();

    const float bY = baseY[c];
    const float vb = ldg<F32>(V_b, cc + c);
    for (int rr = 0; rr < 32; rr += 8) {
        float w[8];
        #pragma unroll
        for (int j = 0; j < 8; j++) w[j] = Yb[(size_t)(j0 + rr + j) * FEAT];
        #pragma unroll
        for (int j = 0; j < 8; j++) {
            const int r = j0 + rr + j;
            const float inv = 1.0f / (S - e0s[r] + eds[r]);
            const float val = (bY + (eds[r] - e0s[r]) * w[j]) * inv + vb;
            stg<F32>(out, (size_t)(b * NN + r) * FEAT + cc + c, val);
        }
    }
}

__global__ __launch_bounds__(384) void k_combine(
    const void* ln_w,
    const float* d0, const float* diag, const float* Y,
    const void* V_b, void* out)
{
    if (is_f32(ln_w))
        combine_body<true >(d0, diag, Y, V_b, out);
    else
        combine_body<false>(d0, diag, Y, V_b, out);
}

extern "C" void kernel_launch(void* const* d_in, const int* in_sizes, int n_in,
                              void* d_out, int out_size, void* d_ws, size_t ws_size,
                              hipStream_t stream) {
    const void* x     = d_in[0];
    const void* U_w   = d_in[1];
    const void* U_b   = d_in[2];
    const void* ln_w  = d_in[3];
    const void* ln_b  = d_in[4];
    const void* enc_w = d_in[5];
    const void* enc_b = d_in[6];
    const void* dec_w = d_in[7];
    const void* dec_b = d_in[8];
    const void* V_w   = d_in[9];
    const void* V_b   = d_in[10];

    float* ws   = (float*)d_ws;
    float* Y    = ws;                     // 512*384  (xh @ V_w, no bias)
    float* d0   = Y + (size_t)BN * FEAT;  // 512
    float* diag = d0 + BN;                // 512

    k_main<<<2 * (BN / 8), 384, 0, stream>>>(x, U_w, U_b, ln_w, ln_b, enc_w, enc_b,
                                             dec_w, dec_b, V_w, Y, d0, diag);
    k_combine<<<4 * BB, 384, 0, stream>>>(ln_w, d0, diag, Y, V_b, d_out);
}

// Round 16
// 104.989 us; speedup vs baseline: 1.1135x; 1.1135x over previous
//
#include <hip/hip_runtime.h>
#include <hip/hip_bf16.h>
#include <math.h>

#define FEAT 384
#define FFN  768
#define ZDIM 384
#define HID  192
#define BB   4
#define NN   128
#define BN   (BB*NN)   // 512 rows

__device__ __forceinline__ float gelu_exact(float x) {
    return 0.5f * x * (1.0f + erff(x * 0.70710678118654752440f));
}

__device__ __forceinline__ float bflo(unsigned u) { return __uint_as_float(u << 16); }
__device__ __forceinline__ float bfhi(unsigned u) { return __uint_as_float(u & 0xFFFF0000u); }

template<bool F32>
__device__ __forceinline__ float ldg(const void* p, int i) {
    if constexpr (F32) return ((const float*)p)[i];
    return __uint_as_float(((unsigned)((const unsigned short*)p)[i]) << 16);
}
template<bool F32>
__device__ __forceinline__ void stg(void* p, size_t i, float v) {
    if constexpr (F32) ((float*)p)[i] = v;
    else ((__hip_bfloat16*)p)[i] = __float2bfloat16(v);
}

// 4-element weight vector: 16B load (fp32) / 8B load (bf16)
template<bool F32> struct V4;
template<> struct V4<true> {
    float4 a;
    __device__ __forceinline__ void load(const void* p, size_t off) {
        a = *(const float4*)((const float*)p + off);
    }
    __device__ __forceinline__ float g(int i) const { return (&a.x)[i]; }
};
template<> struct V4<false> {
    uint2 u;
    __device__ __forceinline__ void load(const void* p, size_t off) {
        u = *(const uint2*)((const unsigned short*)p + off);
    }
    __device__ __forceinline__ float g(int i) const {
        const unsigned w = (&u.x)[i >> 1];
        return (i & 1) ? bfhi(w) : bflo(w);
    }
};

__device__ __forceinline__ bool is_f32(const void* ln_w) {
    return ((const unsigned short*)ln_w)[0] == 0;
}

// ---- block reductions over 384 threads (6 wave64) ----
__device__ __forceinline__ float block_sum(float v, float* sm) {
    for (int o = 32; o > 0; o >>= 1) v += __shfl_down(v, o, 64);
    const int lane = threadIdx.x & 63, w = threadIdx.x >> 6;
    __syncthreads();
    if (lane == 0) sm[w] = v;
    __syncthreads();
    return sm[0] + sm[1] + sm[2] + sm[3] + sm[4] + sm[5];
}
__device__ __forceinline__ float block_max(float v, float* sm) {
    for (int o = 32; o > 0; o >>= 1) v = fmaxf(v, __shfl_down(v, o, 64));
    const int lane = threadIdx.x & 63, w = threadIdx.x >> 6;
    __syncthreads();
    if (lane == 0) sm[w] = v;
    __syncthreads();
    return fmaxf(fmaxf(fmaxf(sm[0], sm[1]), fmaxf(sm[2], sm[3])), fmaxf(sm[4], sm[5]));
}
// 4-wide block sum; sm must hold 24 floats
__device__ __forceinline__ void block_sum4(float v0, float v1, float v2, float v3,
                                           float* sm, float out[4]) {
    for (int o = 32; o > 0; o >>= 1) {
        v0 += __shfl_down(v0, o, 64);
        v1 += __shfl_down(v1, o, 64);
        v2 += __shfl_down(v2, o, 64);
        v3 += __shfl_down(v3, o, 64);
    }
    const int lane = threadIdx.x & 63, w = threadIdx.x >> 6;
    __syncthreads();
    if (lane == 0) { sm[w] = v0; sm[6 + w] = v1; sm[12 + w] = v2; sm[18 + w] = v3; }
    __syncthreads();
    #pragma unroll
    for (int q = 0; q < 4; q++)
        out[q] = sm[q*6] + sm[q*6+1] + sm[q*6+2] + sm[q*6+3] + sm[q*6+4] + sm[q*6+5];
}

// Shared pool (floats): xs 0 (1536), zs 1536 (1536), hid 3072 (768),
// gh 3840 (192) [contiguous after hid => 5th GEMM row], part 4032 (5760),
// sm 9792 (24). Total 9816 = 39.3 KB.
#define SM_TOTAL 9816

// Generic GEMM helper, 3-deep rotating weight staging, EXPLICIT float4 LDS
// reads for the activations (2 x ds_read_b128 per row per 8-K batch instead
// of 8 x ds_read_b32):
// M rows from LDS (in[m*ldin + k]), 4 cols/thread, K-chunk KCH at base kb.
// ldin*4B and kb*4B must be 16B-aligned (ldin in {384,192}, kb mult of 48: ok).
template<bool F32, int KCH, int M>
__device__ __forceinline__ void gemmMx4(
    const void* __restrict__ W, int ldw, int c0, int kb,
    const float* __restrict__ in, int ldin, float acc[M][4])
{
    constexpr int NB = KCH / 8;
    V4<F32> buf[3][8];
    #pragma unroll
    for (int j = 0; j < 8; j++) buf[0][j].load(W, (size_t)(kb + j) * ldw + c0);
    if (NB > 1) {
        #pragma unroll
        for (int j = 0; j < 8; j++) buf[1][j].load(W, (size_t)(kb + 8 + j) * ldw + c0);
    }
    #pragma unroll
    for (int b = 0; b < NB; b++) {
        const int cur = b % 3;
        if (b + 2 < NB) {
            const int nxt = (b + 2) % 3;
            #pragma unroll
            for (int j = 0; j < 8; j++)
                buf[nxt][j].load(W, (size_t)(kb + (b + 2) * 8 + j) * ldw + c0);
        }
        #pragma unroll
        for (int m = 0; m < M; m++) {
            const float4 x0 = *(const float4*)(in + m * ldin + kb + b * 8);
            const float4 x1 = *(const float4*)(in + m * ldin + kb + b * 8 + 4);
            const float xv[8] = {x0.x, x0.y, x0.z, x0.w, x1.x, x1.y, x1.z, x1.w};
            #pragma unroll
            for (int j = 0; j < 8; j++) {
                #pragma unroll
                for (int i = 0; i < 4; i++)
                    acc[m][i] = fmaf(xv[j], buf[cur][j].g(i), acc[m][i]);
            }
        }
    }
}

// ============ Type A: quad q — U z-half -> LN -> enc -> dec -> dots ============
template<bool F32>
__device__ void bodyA(float* S, int q,
    const void* __restrict__ x, const void* __restrict__ U_w,
    const void* __restrict__ U_b, const void* __restrict__ ln_w,
    const void* __restrict__ ln_b, const void* __restrict__ enc_w,
    const void* __restrict__ enc_b, const void* __restrict__ dec_w,
    const void* __restrict__ dec_b,
    float* __restrict__ d0, float* __restrict__ diag)
{
    const int rb = 4 * q;
    const int t = threadIdx.x;
    float* xs = S;          // 4 x 384
    float* zs = S + 1536;   // 4 x 384
    float* hid = S + 3072;  // 4 x 192  (+ gh right after = 5th row)
    float* gh = S + 3840;   // 192
    float* part = S + 4032; // up to 5760
    float* sm = S + 9792;   // 24

    #pragma unroll
    for (int m = 0; m < 4; m++) xs[m * 384 + t] = ldg<F32>(x, (rb + m) * FEAT + t);
    if (t < HID) gh[t] = gelu_exact(ldg<F32>(enc_b, t));
    __syncthreads();

    // ---- U z-half: cg=t%96 -> 4 cols (global 384+4cg); kh=t/96 -> K 96kh..+96 ----
    const int cg = t % 96, kh = t / 96;
    const int cL = 4 * cg, cG = ZDIM + cL, kb = 96 * kh;
    float acc[4][4] = {};
    gemmMx4<F32, 96, 4>(U_w, FFN, cG, kb, xs, 384, acc);
    if (kh > 0) {
        float* p = &part[(kh - 1) * 1536 + cg];
        #pragma unroll
        for (int m = 0; m < 4; m++)
            #pragma unroll
            for (int i = 0; i < 4; i++) p[(m * 4 + i) * 96] = acc[m][i];
    }
    __syncthreads();

    float hv[4][4];
    float s1[4] = {0,0,0,0}, s2[4] = {0,0,0,0};
    if (kh == 0) {
        #pragma unroll
        for (int i = 0; i < 4; i++) {
            const float ub = ldg<F32>(U_b, cG + i);
            #pragma unroll
            for (int m = 0; m < 4; m++) {
                float v = acc[m][i] + ub
                        + part[(m * 4 + i) * 96 + cg]
                        + part[1536 + (m * 4 + i) * 96 + cg]
                        + part[3072 + (m * 4 + i) * 96 + cg];
                v = gelu_exact(v);
                hv[m][i] = v;
                s1[m] += v; s2[m] += v * v;
            }
        }
    }
    float S1[4], S2[4];
    block_sum4(s1[0], s1[1], s1[2], s1[3], sm, S1);
    block_sum4(s2[0], s2[1], s2[2], s2[3], sm, S2);
    if (kh == 0) {
        #pragma unroll
        for (int m = 0; m < 4; m++) {
            const float mu = S1[m] * (1.0f / ZDIM);
            const float rs = rsqrtf(S2[m] * (1.0f / ZDIM) - mu * mu + 1e-5f);
            #pragma unroll
            for (int i = 0; i < 4; i++) {
                const int zc = cL + i;
                zs[m * 384 + zc] = (hv[m][i] - mu) * rs * ldg<F32>(ln_w, zc) + ldg<F32>(ln_b, zc);
            }
        }
    }
    __syncthreads();

    // ---- encoder: cgE=t%48 -> 4 cols of 192; khE=t/48 -> K 48khE..+48 ----
    {
        const int cgE = t % 48, khE = t / 48;
        const int cE = 4 * cgE, kbE = 48 * khE;
        float ea[4][4] = {};
        gemmMx4<F32, 48, 4>(enc_w, HID, cE, kbE, zs, 384, ea);
        if (khE > 0) {
            float* p = &part[(khE - 1) * 768 + cgE];
            #pragma unroll
            for (int m = 0; m < 4; m++)
                #pragma unroll
                for (int i = 0; i < 4; i++) p[(m * 4 + i) * 48] = ea[m][i];
        }
        __syncthreads();
        if (khE == 0) {
            #pragma unroll
            for (int i = 0; i < 4; i++) {
                const float ebv = ldg<F32>(enc_b, cE + i);
                #pragma unroll
                for (int m = 0; m < 4; m++) {
                    float v = ea[m][i] + ebv;
                    #pragma unroll
                    for (int kk = 0; kk < 7; kk++)
                        v += part[kk * 768 + (m * 4 + i) * 48 + cgE];
                    hid[m * 192 + cE + i] = gelu_exact(v);
                }
            }
        }
        __syncthreads();
    }

    // ---- decoder: 5-row GEMM (4 hid rows + gh as row 4) ----
    {
        const int cgD = t % 96, khD = t / 96;
        const int cD = 4 * cgD, kbD = 48 * khD;
        float da[5][4] = {};
        gemmMx4<F32, 48, 5>(dec_w, ZDIM, cD, kbD, hid, 192, da);
        if (khD > 0) {
            float* p = &part[(khD - 1) * 1920 + cgD];
            #pragma unroll
            for (int m = 0; m < 5; m++)
                #pragma unroll
                for (int i = 0; i < 4; i++) p[(m * 4 + i) * 96] = da[m][i];
        }
        __syncthreads();
        float pd[4] = {0,0,0,0}, pe[4] = {0,0,0,0};
        if (khD == 0) {
            #pragma unroll
            for (int i = 0; i < 4; i++) {
                const int c = cD + i;
                const float dbv = ldg<F32>(dec_b, c);
                float vc = da[4][i] + dbv;
                #pragma unroll
                for (int kk = 0; kk < 3; kk++)
                    vc += part[kk * 1920 + (16 + i) * 96 + cgD];
                #pragma unroll
                for (int m = 0; m < 4; m++) {
                    float v = da[m][i] + dbv;
                    #pragma unroll
                    for (int kk = 0; kk < 3; kk++)
                        v += part[kk * 1920 + (m * 4 + i) * 96 + cgD];
                    const float zv = zs[m * 384 + c];
                    pd[m] = fmaf(v, zv, pd[m]);
                    pe[m] = fmaf(vc, zv, pe[m]);
                }
            }
        }
        float DG[4], DD[4];
        block_sum4(pd[0], pd[1], pd[2], pd[3], sm, DG);
        block_sum4(pe[0], pe[1], pe[2], pe[3], sm, DD);
        if (t == 0) {
            #pragma unroll
            for (int m = 0; m < 4; m++) { diag[rb + m] = DG[m]; d0[rb + m] = DD[m]; }
        }
    }
}

// ============ Type B: quad q — U xh-half -> Y = xh @ V_w ============
template<bool F32>
__device__ void bodyB(float* S, int q,
    const void* __restrict__ x, const void* __restrict__ U_w,
    const void* __restrict__ U_b, const void* __restrict__ V_w,
    float* __restrict__ Y)
{
    const int rb = 4 * q;
    const int t = threadIdx.x;
    float* xs = S;          // 4 x 384
    float* zs = S + 1536;   // 4 x 384 (xh)
    float* part = S + 4032;

    #pragma unroll
    for (int m = 0; m < 4; m++) xs[m * 384 + t] = ldg<F32>(x, (rb + m) * FEAT + t);
    __syncthreads();

    const int cg = t % 96, kh = t / 96;
    const int cL = 4 * cg, kb = 96 * kh;
    float acc[4][4] = {};
    gemmMx4<F32, 96, 4>(U_w, FFN, cL, kb, xs, 384, acc);
    if (kh > 0) {
        float* p = &part[(kh - 1) * 1536 + cg];
        #pragma unroll
        for (int m = 0; m < 4; m++)
            #pragma unroll
            for (int i = 0; i < 4; i++) p[(m * 4 + i) * 96] = acc[m][i];
    }
    __syncthreads();
    if (kh == 0) {
        #pragma unroll
        for (int i = 0; i < 4; i++) {
            const float ub = ldg<F32>(U_b, cL + i);
            #pragma unroll
            for (int m = 0; m < 4; m++) {
                float v = acc[m][i] + ub
                        + part[(m * 4 + i) * 96 + cg]
                        + part[1536 + (m * 4 + i) * 96 + cg]
                        + part[3072 + (m * 4 + i) * 96 + cg];
                zs[m * 384 + cL + i] = gelu_exact(v);
            }
        }
    }
    __syncthreads();

    // V: same thread mapping; K = 384 full
    float ya[4][4] = {};
    gemmMx4<F32, 96, 4>(V_w, FEAT, cL, kb, zs, 384, ya);
    if (kh > 0) {
        float* p = &part[(kh - 1) * 1536 + cg];
        #pragma unroll
        for (int m = 0; m < 4; m++)
            #pragma unroll
            for (int i = 0; i < 4; i++) p[(m * 4 + i) * 96] = ya[m][i];
    }
    __syncthreads();
    if (kh == 0) {
        #pragma unroll
        for (int m = 0; m < 4; m++) {
            float o[4];
            #pragma unroll
            for (int i = 0; i < 4; i++) {
                o[i] = ya[m][i]
                     + part[(m * 4 + i) * 96 + cg]
                     + part[1536 + (m * 4 + i) * 96 + cg]
                     + part[3072 + (m * 4 + i) * 96 + cg];
            }
            *(float4*)(Y + (size_t)(rb + m) * FEAT + cL) = make_float4(o[0], o[1], o[2], o[3]);
        }
    }
}

__global__ __launch_bounds__(384) void k_main(
    const void* x, const void* U_w, const void* U_b,
    const void* ln_w, const void* ln_b,
    const void* enc_w, const void* enc_b,
    const void* dec_w, const void* dec_b, const void* V_w,
    float* Y, float* d0, float* diag)
{
    __shared__ float S[SM_TOTAL];   // single pool for all template paths
    const int type = blockIdx.x & 1;
    const int q = blockIdx.x >> 1;
    if (is_f32(ln_w)) {
        if (type == 0) bodyA<true >(S, q, x, U_w, U_b, ln_w, ln_b, enc_w, enc_b, dec_w, dec_b, d0, diag);
        else           bodyB<true >(S, q, x, U_w, U_b, V_w, Y);
    } else {
        if (type == 0) bodyA<false>(S, q, x, U_w, U_b, ln_w, ln_b, enc_w, enc_b, dec_w, dec_b, d0, diag);
        else           bodyB<false>(S, q, x, U_w, U_b, V_w, Y);
    }
}

// ============ K2: 16 blocks = 4 batches x 4 col-chunks of 96 ============
// out_i = (baseY + (ed_i - e0_i) * Y_i) / (S - e0_i + ed_i) + V_b
template<bool F32>
__device__ void combine_body(
    const float* __restrict__ d0, const float* __restrict__ diag,
    const float* __restrict__ Y,
    const void* __restrict__ V_b, void* __restrict__ out)
{
    const int b  = blockIdx.x >> 2;
    const int cc = (blockIdx.x & 3) * 96;
    const int t = threadIdx.x;
    const int c = t % 96, qq = t / 96;
    __shared__ float e0s[NN], eds[NN];
    __shared__ float bp[4 * 96];
    __shared__ float baseY[96];
    __shared__ float sm[12];

    float d0v = -INFINITY, dgv = -INFINITY;
    if (t < NN) { d0v = d0[b * NN + t]; dgv = diag[b * NN + t]; }
    const float m = block_max(fmaxf(d0v, dgv), sm);
    float e0v = 0.f;
    if (t < NN) {
        e0v = expf(d0v - m);
        e0s[t] = e0v;
        eds[t] = expf(dgv - m);
    }
    const float S = block_sum(e0v, sm);

    const float* Yb = Y + (size_t)b * NN * FEAT + cc + c;
    const int j0 = 32 * qq;
    float p = 0.f;
    for (int jj = 0; jj < 32; jj += 8) {
        float w[8];
        #pragma unroll
        for (int j = 0; j < 8; j++) w[j] = Yb[(size_t)(j0 + jj + j) * FEAT];
        #pragma unroll
        for (int j = 0; j < 8; j++) p = fmaf(e0s[j0 + jj + j], w[j], p);
    }
    bp[qq * 96 + c] = p;
    __syncthreads();
    if (qq == 0) baseY[c] = bp[c] + bp[96 + c] + bp[192 + c] + bp[288 + c];
    __syncthreads();

    const float bY = baseY[c];
    const float vb = ldg<F32>(V_b, cc + c);
    for (int rr = 0; rr < 32; rr += 8) {
        float w[8];
        #pragma unroll
        for (int j = 0; j < 8; j++) w[j] = Yb[(size_t)(j0 + rr + j) * FEAT];
        #pragma unroll
        for (int j = 0; j < 8; j++) {
            const int r = j0 + rr + j;
            const float inv = 1.0f / (S - e0s[r] + eds[r]);
            const float val = (bY + (eds[r] - e0s[r]) * w[j]) * inv + vb;
            stg<F32>(out, (size_t)(b * NN + r) * FEAT + cc + c, val);
        }
    }
}

__global__ __launch_bounds__(384) void k_combine(
    const void* ln_w,
    const float* d0, const float* diag, const float* Y,
    const void* V_b, void* out)
{
    if (is_f32(ln_w))
        combine_body<true >(d0, diag, Y, V_b, out);
    else
        combine_body<false>(d0, diag, Y, V_b, out);
}

extern "C" void kernel_launch(void* const* d_in, const int* in_sizes, int n_in,
                              void* d_out, int out_size, void* d_ws, size_t ws_size,
                              hipStream_t stream) {
    const void* x     = d_in[0];
    const void* U_w   = d_in[1];
    const void* U_b   = d_in[2];
    const void* ln_w  = d_in[3];
    const void* ln_b  = d_in[4];
    const void* enc_w = d_in[5];
    const void* enc_b = d_in[6];
    const void* dec_w = d_in[7];
    const void* dec_b = d_in[8];
    const void* V_w   = d_in[9];
    const void* V_b   = d_in[10];

    float* ws   = (float*)d_ws;
    float* Y    = ws;                     // 512*384  (xh @ V_w, no bias)
    float* d0   = Y + (size_t)BN * FEAT;  // 512
    float* diag = d0 + BN;                // 512

    k_main<<<2 * (BN / 4), 384, 0, stream>>>(x, U_w, U_b, ln_w, ln_b, enc_w, enc_b,
                                             dec_w, dec_b, V_w, Y, d0, diag);
    k_combine<<<4 * BB, 384, 0, stream>>>(ln_w, d0, diag, Y, V_b, d_out);
}

// Round 17
// 101.988 us; speedup vs baseline: 1.1462x; 1.0294x over previous
//
#include <hip/hip_runtime.h>
#include <hip/hip_bf16.h>
#include <math.h>

#define FEAT 384
#define FFN  768
#define ZDIM 384
#define HID  192
#define BB   4
#define NN   128
#define BN   (BB*NN)   // 512 rows

__device__ __forceinline__ float gelu_exact(float x) {
    return 0.5f * x * (1.0f + erff(x * 0.70710678118654752440f));
}

__device__ __forceinline__ float bflo(unsigned u) { return __uint_as_float(u << 16); }
__device__ __forceinline__ float bfhi(unsigned u) { return __uint_as_float(u & 0xFFFF0000u); }

template<bool F32>
__device__ __forceinline__ float ldg(const void* p, int i) {
    if constexpr (F32) return ((const float*)p)[i];
    return __uint_as_float(((unsigned)((const unsigned short*)p)[i]) << 16);
}
template<bool F32>
__device__ __forceinline__ void stg(void* p, size_t i, float v) {
    if constexpr (F32) ((float*)p)[i] = v;
    else ((__hip_bfloat16*)p)[i] = __float2bfloat16(v);
}

// 4-element weight vector: 16B load (fp32) / 8B load (bf16)
template<bool F32> struct V4;
template<> struct V4<true> {
    float4 a;
    __device__ __forceinline__ void load(const void* p, size_t off) {
        a = *(const float4*)((const float*)p + off);
    }
    __device__ __forceinline__ float g(int i) const { return (&a.x)[i]; }
};
template<> struct V4<false> {
    uint2 u;
    __device__ __forceinline__ void load(const void* p, size_t off) {
        u = *(const uint2*)((const unsigned short*)p + off);
    }
    __device__ __forceinline__ float g(int i) const {
        const unsigned w = (&u.x)[i >> 1];
        return (i & 1) ? bfhi(w) : bflo(w);
    }
};

__device__ __forceinline__ bool is_f32(const void* ln_w) {
    return ((const unsigned short*)ln_w)[0] == 0;
}

// ---- block reductions over 384 threads (6 wave64) ----
__device__ __forceinline__ float block_sum(float v, float* sm) {
    for (int o = 32; o > 0; o >>= 1) v += __shfl_down(v, o, 64);
    const int lane = threadIdx.x & 63, w = threadIdx.x >> 6;
    __syncthreads();
    if (lane == 0) sm[w] = v;
    __syncthreads();
    return sm[0] + sm[1] + sm[2] + sm[3] + sm[4] + sm[5];
}
__device__ __forceinline__ float block_max(float v, float* sm) {
    for (int o = 32; o > 0; o >>= 1) v = fmaxf(v, __shfl_down(v, o, 64));
    const int lane = threadIdx.x & 63, w = threadIdx.x >> 6;
    __syncthreads();
    if (lane == 0) sm[w] = v;
    __syncthreads();
    return fmaxf(fmaxf(fmaxf(sm[0], sm[1]), fmaxf(sm[2], sm[3])), fmaxf(sm[4], sm[5]));
}
// 8-wide block sum (one barrier pair for 8 values); sm must hold 48 floats
__device__ __forceinline__ void block_sum8(const float v[8], float* sm, float out[8]) {
    float tv[8];
    #pragma unroll
    for (int n = 0; n < 8; n++) tv[n] = v[n];
    for (int o = 32; o > 0; o >>= 1) {
        #pragma unroll
        for (int n = 0; n < 8; n++) tv[n] += __shfl_down(tv[n], o, 64);
    }
    const int lane = threadIdx.x & 63, w = threadIdx.x >> 6;
    __syncthreads();
    if (lane == 0) {
        #pragma unroll
        for (int n = 0; n < 8; n++) sm[n * 6 + w] = tv[n];
    }
    __syncthreads();
    #pragma unroll
    for (int n = 0; n < 8; n++)
        out[n] = sm[n*6] + sm[n*6+1] + sm[n*6+2] + sm[n*6+3] + sm[n*6+4] + sm[n*6+5];
}

// Shared pool (floats): xs 0 (1536), zs 1536 (1536), hid 3072 (768),
// gh 3840 (192) [contiguous after hid => 5th GEMM row], part 4032 (5760),
// sm 9792 (48). Total 9840 = 39.4 KB.
#define SM_TOTAL 9840

// Generic GEMM helper, 3-deep rotating weight staging, float4 LDS activation
// reads. M rows from LDS (in[m*ldin + k]), 4 cols/thread, K-chunk KCH at kb.
template<bool F32, int KCH, int M>
__device__ __forceinline__ void gemmMx4(
    const void* __restrict__ W, int ldw, int c0, int kb,
    const float* __restrict__ in, int ldin, float acc[M][4])
{
    constexpr int NB = KCH / 8;
    V4<F32> buf[3][8];
    #pragma unroll
    for (int j = 0; j < 8; j++) buf[0][j].load(W, (size_t)(kb + j) * ldw + c0);
    if (NB > 1) {
        #pragma unroll
        for (int j = 0; j < 8; j++) buf[1][j].load(W, (size_t)(kb + 8 + j) * ldw + c0);
    }
    #pragma unroll
    for (int b = 0; b < NB; b++) {
        const int cur = b % 3;
        if (b + 2 < NB) {
            const int nxt = (b + 2) % 3;
            #pragma unroll
            for (int j = 0; j < 8; j++)
                buf[nxt][j].load(W, (size_t)(kb + (b + 2) * 8 + j) * ldw + c0);
        }
        #pragma unroll
        for (int m = 0; m < M; m++) {
            const float4 x0 = *(const float4*)(in + m * ldin + kb + b * 8);
            const float4 x1 = *(const float4*)(in + m * ldin + kb + b * 8 + 4);
            const float xv[8] = {x0.x, x0.y, x0.z, x0.w, x1.x, x1.y, x1.z, x1.w};
            #pragma unroll
            for (int j = 0; j < 8; j++) {
                #pragma unroll
                for (int i = 0; i < 4; i++)
                    acc[m][i] = fmaf(xv[j], buf[cur][j].g(i), acc[m][i]);
            }
        }
    }
}

// ============ Type A: quad q — U z-half -> LN -> enc -> dec -> dots ============
template<bool F32>
__device__ void bodyA(float* S, int q,
    const void* __restrict__ x, const void* __restrict__ U_w,
    const void* __restrict__ U_b, const void* __restrict__ ln_w,
    const void* __restrict__ ln_b, const void* __restrict__ enc_w,
    const void* __restrict__ enc_b, const void* __restrict__ dec_w,
    const void* __restrict__ dec_b,
    float* __restrict__ d0, float* __restrict__ diag)
{
    const int rb = 4 * q;
    const int t = threadIdx.x;
    float* xs = S;          // 4 x 384
    float* zs = S + 1536;   // 4 x 384
    float* hid = S + 3072;  // 4 x 192  (+ gh right after = 5th row)
    float* gh = S + 3840;   // 192
    float* part = S + 4032; // up to 5760
    float* sm = S + 9792;   // 48

    #pragma unroll
    for (int m = 0; m < 4; m++) xs[m * 384 + t] = ldg<F32>(x, (rb + m) * FEAT + t);
    if (t < HID) gh[t] = gelu_exact(ldg<F32>(enc_b, t));
    __syncthreads();

    // ---- U z-half: cg=t%96 -> 4 cols (global 384+4cg); kh=t/96 -> K 96kh..+96 ----
    const int cg = t % 96, kh = t / 96;
    const int cL = 4 * cg, cG = ZDIM + cL, kb = 96 * kh;
    float acc[4][4] = {};
    gemmMx4<F32, 96, 4>(U_w, FFN, cG, kb, xs, 384, acc);
    if (kh > 0) {
        float* p = &part[(kh - 1) * 1536 + cg];
        #pragma unroll
        for (int m = 0; m < 4; m++)
            #pragma unroll
            for (int i = 0; i < 4; i++) p[(m * 4 + i) * 96] = acc[m][i];
    }
    __syncthreads();

    float hv[4][4];
    float sv[8] = {};
    if (kh == 0) {
        #pragma unroll
        for (int i = 0; i < 4; i++) {
            const float ub = ldg<F32>(U_b, cG + i);
            #pragma unroll
            for (int m = 0; m < 4; m++) {
                float v = acc[m][i] + ub
                        + part[(m * 4 + i) * 96 + cg]
                        + part[1536 + (m * 4 + i) * 96 + cg]
                        + part[3072 + (m * 4 + i) * 96 + cg];
                v = gelu_exact(v);
                hv[m][i] = v;
                sv[m] += v;           // s1
                sv[4 + m] += v * v;   // s2
            }
        }
    }
    float SS[8];
    block_sum8(sv, sm, SS);   // one barrier pair for both moments
    if (kh == 0) {
        #pragma unroll
        for (int m = 0; m < 4; m++) {
            const float mu = SS[m] * (1.0f / ZDIM);
            const float rs = rsqrtf(SS[4 + m] * (1.0f / ZDIM) - mu * mu + 1e-5f);
            #pragma unroll
            for (int i = 0; i < 4; i++) {
                const int zc = cL + i;
                zs[m * 384 + zc] = (hv[m][i] - mu) * rs * ldg<F32>(ln_w, zc) + ldg<F32>(ln_b, zc);
            }
        }
    }
    __syncthreads();

    // ---- encoder: cgE=t%48 -> 4 cols of 192; khE=t/48 -> K 48khE..+48 ----
    {
        const int cgE = t % 48, khE = t / 48;
        const int cE = 4 * cgE, kbE = 48 * khE;
        float ea[4][4] = {};
        gemmMx4<F32, 48, 4>(enc_w, HID, cE, kbE, zs, 384, ea);
        if (khE > 0) {
            float* p = &part[(khE - 1) * 768 + cgE];
            #pragma unroll
            for (int m = 0; m < 4; m++)
                #pragma unroll
                for (int i = 0; i < 4; i++) p[(m * 4 + i) * 48] = ea[m][i];
        }
        __syncthreads();
        if (khE == 0) {
            #pragma unroll
            for (int i = 0; i < 4; i++) {
                const float ebv = ldg<F32>(enc_b, cE + i);
                #pragma unroll
                for (int m = 0; m < 4; m++) {
                    float v = ea[m][i] + ebv;
                    #pragma unroll
                    for (int kk = 0; kk < 7; kk++)
                        v += part[kk * 768 + (m * 4 + i) * 48 + cgE];
                    hid[m * 192 + cE + i] = gelu_exact(v);
                }
            }
        }
        __syncthreads();
    }

    // ---- decoder: 5-row GEMM (4 hid rows + gh as row 4) ----
    {
        const int cgD = t % 96, khD = t / 96;
        const int cD = 4 * cgD, kbD = 48 * khD;
        float da[5][4] = {};
        gemmMx4<F32, 48, 5>(dec_w, ZDIM, cD, kbD, hid, 192, da);
        if (khD > 0) {
            float* p = &part[(khD - 1) * 1920 + cgD];
            #pragma unroll
            for (int m = 0; m < 5; m++)
                #pragma unroll
                for (int i = 0; i < 4; i++) p[(m * 4 + i) * 96] = da[m][i];
        }
        __syncthreads();
        float dv[8] = {};
        if (khD == 0) {
            #pragma unroll
            for (int i = 0; i < 4; i++) {
                const int c = cD + i;
                const float dbv = ldg<F32>(dec_b, c);
                float vc = da[4][i] + dbv;
                #pragma unroll
                for (int kk = 0; kk < 3; kk++)
                    vc += part[kk * 1920 + (16 + i) * 96 + cgD];
                #pragma unroll
                for (int m = 0; m < 4; m++) {
                    float v = da[m][i] + dbv;
                    #pragma unroll
                    for (int kk = 0; kk < 3; kk++)
                        v += part[kk * 1920 + (m * 4 + i) * 96 + cgD];
                    const float zv = zs[m * 384 + c];
                    dv[m] = fmaf(v, zv, dv[m]);        // diag partial
                    dv[4 + m] = fmaf(vc, zv, dv[4 + m]); // d0 partial
                }
            }
        }
        float DD8[8];
        block_sum8(dv, sm, DD8);   // one barrier pair for both dot sets
        if (t == 0) {
            #pragma unroll
            for (int m = 0; m < 4; m++) { diag[rb + m] = DD8[m]; d0[rb + m] = DD8[4 + m]; }
        }
    }
}

// ============ Type B: quad q — U xh-half -> Y = xh @ V_w ============
template<bool F32>
__device__ void bodyB(float* S, int q,
    const void* __restrict__ x, const void* __restrict__ U_w,
    const void* __restrict__ U_b, const void* __restrict__ V_w,
    float* __restrict__ Y)
{
    const int rb = 4 * q;
    const int t = threadIdx.x;
    float* xs = S;          // 4 x 384
    float* zs = S + 1536;   // 4 x 384 (xh)
    float* part = S + 4032;

    #pragma unroll
    for (int m = 0; m < 4; m++) xs[m * 384 + t] = ldg<F32>(x, (rb + m) * FEAT + t);
    __syncthreads();

    const int cg = t % 96, kh = t / 96;
    const int cL = 4 * cg, kb = 96 * kh;
    float acc[4][4] = {};
    gemmMx4<F32, 96, 4>(U_w, FFN, cL, kb, xs, 384, acc);
    if (kh > 0) {
        float* p = &part[(kh - 1) * 1536 + cg];
        #pragma unroll
        for (int m = 0; m < 4; m++)
            #pragma unroll
            for (int i = 0; i < 4; i++) p[(m * 4 + i) * 96] = acc[m][i];
    }
    __syncthreads();
    if (kh == 0) {
        #pragma unroll
        for (int i = 0; i < 4; i++) {
            const float ub = ldg<F32>(U_b, cL + i);
            #pragma unroll
            for (int m = 0; m < 4; m++) {
                float v = acc[m][i] + ub
                        + part[(m * 4 + i) * 96 + cg]
                        + part[1536 + (m * 4 + i) * 96 + cg]
                        + part[3072 + (m * 4 + i) * 96 + cg];
                zs[m * 384 + cL + i] = gelu_exact(v);
            }
        }
    }
    __syncthreads();

    // V: same thread mapping; K = 384 full
    float ya[4][4] = {};
    gemmMx4<F32, 96, 4>(V_w, FEAT, cL, kb, zs, 384, ya);
    if (kh > 0) {
        float* p = &part[(kh - 1) * 1536 + cg];
        #pragma unroll
        for (int m = 0; m < 4; m++)
            #pragma unroll
            for (int i = 0; i < 4; i++) p[(m * 4 + i) * 96] = ya[m][i];
    }
    __syncthreads();
    if (kh == 0) {
        #pragma unroll
        for (int m = 0; m < 4; m++) {
            float o[4];
            #pragma unroll
            for (int i = 0; i < 4; i++) {
                o[i] = ya[m][i]
                     + part[(m * 4 + i) * 96 + cg]
                     + part[1536 + (m * 4 + i) * 96 + cg]
                     + part[3072 + (m * 4 + i) * 96 + cg];
            }
            *(float4*)(Y + (size_t)(rb + m) * FEAT + cL) = make_float4(o[0], o[1], o[2], o[3]);
        }
    }
}

__global__ __launch_bounds__(384) void k_main(
    const void* x, const void* U_w, const void* U_b,
    const void* ln_w, const void* ln_b,
    const void* enc_w, const void* enc_b,
    const void* dec_w, const void* dec_b, const void* V_w,
    float* Y, float* d0, float* diag)
{
    __shared__ float S[SM_TOTAL];   // single pool for all template paths
    const int type = blockIdx.x & 1;
    const int q = blockIdx.x >> 1;
    if (is_f32(ln_w)) {
        if (type == 0) bodyA<true >(S, q, x, U_w, U_b, ln_w, ln_b, enc_w, enc_b, dec_w, dec_b, d0, diag);
        else           bodyB<true >(S, q, x, U_w, U_b, V_w, Y);
    } else {
        if (type == 0) bodyA<false>(S, q, x, U_w, U_b, ln_w, ln_b, enc_w, enc_b, dec_w, dec_b, d0, diag);
        else           bodyB<false>(S, q, x, U_w, U_b, V_w, Y);
    }
}

// ============ K2: 64 blocks = 4 batches x 16 col-chunks of 24 ============
// out_i = (baseY + (ed_i - e0_i) * Y_i) / (S - e0_i + ed_i) + V_b
// Y row-chunk kept in registers between base pass and output pass.
template<bool F32>
__device__ void combine_body(
    const float* __restrict__ d0, const float* __restrict__ diag,
    const float* __restrict__ Y,
    const void* __restrict__ V_b, void* __restrict__ out)
{
    const int b  = blockIdx.x >> 4;
    const int cc = (blockIdx.x & 15) * 24;
    const int t = threadIdx.x;
    const int c = t % 24, qq = t / 24;      // 16 row-groups of 8 rows
    __shared__ float e0s[NN], eds[NN];
    __shared__ float bp[16 * 24];
    __shared__ float baseY[24];
    __shared__ float sm[12];

    float d0v = -INFINITY, dgv = -INFINITY;
    if (t < NN) { d0v = d0[b * NN + t]; dgv = diag[b * NN + t]; }
    const float m = block_max(fmaxf(d0v, dgv), sm);
    float e0v = 0.f;
    if (t < NN) {
        e0v = expf(d0v - m);
        e0s[t] = e0v;
        eds[t] = expf(dgv - m);
    }
    const float S = block_sum(e0v, sm);     // internal syncs publish e0s/eds

    const float* Yb = Y + (size_t)b * NN * FEAT + cc + c;
    const int j0 = 8 * qq;
    float w[8];
    #pragma unroll
    for (int j = 0; j < 8; j++) w[j] = Yb[(size_t)(j0 + j) * FEAT];
    float p = 0.f;
    #pragma unroll
    for (int j = 0; j < 8; j++) p = fmaf(e0s[j0 + j], w[j], p);
    bp[qq * 24 + c] = p;
    __syncthreads();
    if (qq == 0) {
        float s = 0.f;
        #pragma unroll
        for (int g = 0; g < 16; g++) s += bp[g * 24 + c];
        baseY[c] = s;
    }
    __syncthreads();

    const float bY = baseY[c];
    const float vb = ldg<F32>(V_b, cc + c);
    #pragma unroll
    for (int j = 0; j < 8; j++) {
        const int r = j0 + j;
        const float inv = 1.0f / (S - e0s[r] + eds[r]);
        const float val = (bY + (eds[r] - e0s[r]) * w[j]) * inv + vb;
        stg<F32>(out, (size_t)(b * NN + r) * FEAT + cc + c, val);
    }
}

__global__ __launch_bounds__(384) void k_combine(
    const void* ln_w,
    const float* d0, const float* diag, const float* Y,
    const void* V_b, void* out)
{
    if (is_f32(ln_w))
        combine_body<true >(d0, diag, Y, V_b, out);
    else
        combine_body<false>(d0, diag, Y, V_b, out);
}

extern "C" void kernel_launch(void* const* d_in, const int* in_sizes, int n_in,
                              void* d_out, int out_size, void* d_ws, size_t ws_size,
                              hipStream_t stream) {
    const void* x     = d_in[0];
    const void* U_w   = d_in[1];
    const void* U_b   = d_in[2];
    const void* ln_w  = d_in[3];
    const void* ln_b  = d_in[4];
    const void* enc_w = d_in[5];
    const void* enc_b = d_in[6];
    const void* dec_w = d_in[7];
    const void* dec_b = d_in[8];
    const void* V_w   = d_in[9];
    const void* V_b   = d_in[10];

    float* ws   = (float*)d_ws;
    float* Y    = ws;                     // 512*384  (xh @ V_w, no bias)
    float* d0   = Y + (size_t)BN * FEAT;  // 512
    float* diag = d0 + BN;                // 512

    k_main<<<2 * (BN / 4), 384, 0, stream>>>(x, U_w, U_b, ln_w, ln_b, enc_w, enc_b,
                                             dec_w, dec_b, V_w, Y, d0, diag);
    k_combine<<<16 * BB, 384, 0, stream>>>(ln_w, d0, diag, Y, V_b, d_out);
}